// Round 1
// baseline (357.059 us; speedup 1.0000x reference)
//
#include <hip/hip_runtime.h>
#include <cstdint>
#include <cstring>

// Problem constants
#define Bn   32
#define Cn   256
#define Hn   56
#define Wn   56
#define HWn  (Hn*Wn)           // 3136
#define NTOT (Bn*Cn*HWn)       // 25690112
#define WELEMS (Cn*Cn*9)       // 589824
#define EPSv 1e-5f

// ws layout (floats for the stats block)
#define F_WABS  0
#define F_SUM   64
#define F_SQ    320
#define F_SCALE 576
#define F_SHIFT 832
#define STATS_BYTES 4352
#define WB_OFF_BYTES  8192      // uint32 wb[256][9][8]  = 73728 B
#define XB_OFF_BYTES  131072    // uint32 xb[B*HW][8]    = 3211264 B

// ---------------------------------------------------------------------------
// Pack weights: wb[co][t=kh*3+kw][wd] bits over ci (bit=1 <=> w<0),
// and reduce sum(|clip(w,-1,1)|) into ws[F_WABS].
__global__ void pack_w_kernel(const float* __restrict__ w,
                              float* __restrict__ wsf,
                              uint32_t* __restrict__ wb) {
    int u = blockIdx.x * 256 + threadIdx.x;   // 72*256 = 18432 words exactly
    float sabs = 0.0f;
    {
        int co = u / 72;
        int r  = u % 72;
        int t  = r >> 3;         // kh*3+kw
        int wd = r & 7;
        uint32_t bits = 0;
        // w layout OIHW: idx = (co*256 + ci)*9 + t
        const float* wp = w + (size_t)co * 2304 + (size_t)(wd * 32) * 9 + t;
        #pragma unroll
        for (int j = 0; j < 32; j++) {
            float wv = wp[(size_t)j * 9];
            sabs += fminf(fabsf(wv), 1.0f);
            bits |= (__float_as_uint(wv) >> 31) << j;
        }
        wb[u] = bits;
    }
    // block reduce sabs -> one atomic per block
    #pragma unroll
    for (int off = 32; off; off >>= 1) sabs += __shfl_down(sabs, off);
    __shared__ float sh[4];
    if ((threadIdx.x & 63) == 0) sh[threadIdx.x >> 6] = sabs;
    __syncthreads();
    if (threadIdx.x == 0)
        atomicAdd(&wsf[F_WABS], sh[0] + sh[1] + sh[2] + sh[3]);
}

// ---------------------------------------------------------------------------
// Pack activations: xb[b*HW + p][8 words], bit=1 <=> x<0. Pixel-major,
// interleaved words so a 3-pixel neighborhood is 96 contiguous bytes.
__global__ void pack_x_kernel(const float* __restrict__ x,
                              uint32_t* __restrict__ xb) {
    int v = blockIdx.x * 256 + threadIdx.x;   // 392*256 = 100352 exactly
    int b = v / HWn;
    int p = v % HWn;
    const float* xp = x + (size_t)b * Cn * HWn + p;
    uint32_t r[8];
    #pragma unroll
    for (int wd = 0; wd < 8; wd++) {
        uint32_t bits = 0;
        #pragma unroll
        for (int j = 0; j < 32; j++) {
            bits |= (__float_as_uint(xp[(size_t)(wd * 32 + j) * HWn]) >> 31) << j;
        }
        r[wd] = bits;
    }
    uint4* d = (uint4*)xb + (size_t)v * 2;
    d[0] = make_uint4(r[0], r[1], r[2], r[3]);
    d[1] = make_uint4(r[4], r[5], r[6], r[7]);
}

// ---------------------------------------------------------------------------
// Binary conv + identity shortcut. Block: 4 rows x 64 lanes (56 active),
// 4 output channels per thread. Writes pre-BN result to out.
__global__ __launch_bounds__(256) void conv_kernel(
    const uint32_t* __restrict__ xb, const uint32_t* __restrict__ wb,
    const float* __restrict__ x, const float* __restrict__ wsf,
    float* __restrict__ out) {
    const int by  = blockIdx.x;   // 0..13 (y tiles of 4)
    const int cog = blockIdx.y;   // 0..63 (co groups of 4)
    const int b   = blockIdx.z;   // 0..31
    const int tid = threadIdx.x;
    const int ty = tid >> 6, tx = tid & 63;
    const int y = by * 4 + ty;
    const bool active = tx < Wn;
    const int lx = tx < 55 ? tx : 55;   // clamp so loads stay in-bounds

    const float mean_val = wsf[F_WABS] * (1.0f / (float)WELEMS);

    // Load 3-row x 3-pixel neighborhood: per row 96 contiguous bytes.
    uint32_t nw[3][24];
    #pragma unroll
    for (int dh = 0; dh < 3; dh++) {
        int yy = y + dh - 1;
        int yc = yy < 0 ? 0 : (yy > 55 ? 55 : yy);
        const uint4* p = (const uint4*)xb + ((size_t)(b * HWn + yc * Wn + lx) * 2) - 2;
        uint4 q0 = p[0], q1 = p[1], q2 = p[2], q3 = p[3], q4 = p[4], q5 = p[5];
        nw[dh][0]=q0.x;  nw[dh][1]=q0.y;  nw[dh][2]=q0.z;  nw[dh][3]=q0.w;
        nw[dh][4]=q1.x;  nw[dh][5]=q1.y;  nw[dh][6]=q1.z;  nw[dh][7]=q1.w;
        nw[dh][8]=q2.x;  nw[dh][9]=q2.y;  nw[dh][10]=q2.z; nw[dh][11]=q2.w;
        nw[dh][12]=q3.x; nw[dh][13]=q3.y; nw[dh][14]=q3.z; nw[dh][15]=q3.w;
        nw[dh][16]=q4.x; nw[dh][17]=q4.y; nw[dh][18]=q4.z; nw[dh][19]=q4.w;
        nw[dh][20]=q5.x; nw[dh][21]=q5.y; nw[dh][22]=q5.z; nw[dh][23]=q5.w;
    }

    const int co0 = cog * 4;
    int pop[4] = {0, 0, 0, 0};
    int nv = 0;
    #pragma unroll
    for (int dh = 0; dh < 3; dh++) {
        bool rok = (unsigned)(y + dh - 1) < 56u;
        #pragma unroll
        for (int dw = 0; dw < 3; dw++) {
            bool ok = rok && ((unsigned)(tx + dw - 1) < 56u);
            if (ok) {
                nv++;
                #pragma unroll
                for (int cs = 0; cs < 4; cs++) {
                    // wave-uniform address -> scalar loads
                    const uint32_t* wp = wb + (size_t)(co0 + cs) * 72 + (dh * 3 + dw) * 8;
                    int pc = 0;
                    #pragma unroll
                    for (int wd = 0; wd < 8; wd++)
                        pc += __popc(nw[dh][dw * 8 + wd] ^ wp[wd]);
                    pop[cs] += pc;
                }
            }
        }
    }

    if (active) {
        #pragma unroll
        for (int cs = 0; cs < 4; cs++) {
            int c = co0 + cs;
            size_t idx = (size_t)(b * Cn + c) * HWn + y * Wn + tx;
            float dot = (float)(256 * nv - 2 * pop[cs]);
            out[idx] = mean_val * dot + x[idx];
        }
    }
}

// ---------------------------------------------------------------------------
// Per-channel stats: one block per (b,c) plane; atomics into ws.
__global__ void stats_kernel(const float* __restrict__ out,
                             float* __restrict__ wsf) {
    int plane = blockIdx.x;   // b*256 + c
    const float4* p = (const float4*)(out + (size_t)plane * HWn);
    float s = 0.0f, q = 0.0f;
    for (int i = threadIdx.x; i < HWn / 4; i += 256) {
        float4 v = p[i];
        s += v.x + v.y + v.z + v.w;
        q += v.x * v.x + v.y * v.y + v.z * v.z + v.w * v.w;
    }
    #pragma unroll
    for (int off = 32; off; off >>= 1) {
        s += __shfl_down(s, off);
        q += __shfl_down(q, off);
    }
    __shared__ float ss[4], sq[4];
    if ((threadIdx.x & 63) == 0) { ss[threadIdx.x >> 6] = s; sq[threadIdx.x >> 6] = q; }
    __syncthreads();
    if (threadIdx.x == 0) {
        int c = plane & 255;
        atomicAdd(&wsf[F_SUM + c], ss[0] + ss[1] + ss[2] + ss[3]);
        atomicAdd(&wsf[F_SQ  + c], sq[0] + sq[1] + sq[2] + sq[3]);
    }
}

// ---------------------------------------------------------------------------
__global__ void bnfinal_kernel(const float* __restrict__ g,
                               const float* __restrict__ bt,
                               float* __restrict__ wsf) {
    int c = threadIdx.x;
    const float n = (float)(Bn * HWn);
    float mean = wsf[F_SUM + c] / n;
    float var  = wsf[F_SQ + c] / n - mean * mean;
    float sc = g[c] * rsqrtf(var + EPSv);
    wsf[F_SCALE + c] = sc;
    wsf[F_SHIFT + c] = bt[c] - mean * sc;
}

// ---------------------------------------------------------------------------
// Normalize + ReLU, in-place on d_out, float4.
__global__ void epilogue_kernel(float* __restrict__ out,
                                const float* __restrict__ wsf) {
    int i = blockIdx.x * 256 + threadIdx.x;   // 25088*256 = NTOT/4 exactly
    float4* o4 = (float4*)out;
    float4 v = o4[i];
    int c = (i / (HWn / 4)) & 255;
    float sc = wsf[F_SCALE + c];
    float sh = wsf[F_SHIFT + c];
    v.x = fmaxf(v.x * sc + sh, 0.0f);
    v.y = fmaxf(v.y * sc + sh, 0.0f);
    v.z = fmaxf(v.z * sc + sh, 0.0f);
    v.w = fmaxf(v.w * sc + sh, 0.0f);
    o4[i] = v;
}

// ---------------------------------------------------------------------------
extern "C" void kernel_launch(void* const* d_in, const int* in_sizes, int n_in,
                              void* d_out, int out_size, void* d_ws, size_t ws_size,
                              hipStream_t stream) {
    const float* x     = (const float*)d_in[0];
    const float* w     = (const float*)d_in[1];
    const float* gamma = (const float*)d_in[2];
    const float* beta  = (const float*)d_in[3];
    float* out = (float*)d_out;

    float*    wsf = (float*)d_ws;
    uint32_t* wb  = (uint32_t*)((char*)d_ws + WB_OFF_BYTES);
    uint32_t* xb  = (uint32_t*)((char*)d_ws + XB_OFF_BYTES);

    hipMemsetAsync(d_ws, 0, STATS_BYTES, stream);
    pack_w_kernel<<<dim3(72), dim3(256), 0, stream>>>(w, wsf, wb);
    pack_x_kernel<<<dim3(392), dim3(256), 0, stream>>>(x, xb);
    conv_kernel<<<dim3(14, 64, 32), dim3(256), 0, stream>>>(xb, wb, x, wsf, out);
    stats_kernel<<<dim3(Bn * Cn), dim3(256), 0, stream>>>(out, wsf);
    bnfinal_kernel<<<dim3(1), dim3(256), 0, stream>>>(gamma, beta, wsf);
    epilogue_kernel<<<dim3(NTOT / 4 / 256), dim3(256), 0, stream>>>(out, wsf);
}

// Round 2
// 354.493 us; speedup vs baseline: 1.0072x; 1.0072x over previous
//
#include <hip/hip_runtime.h>
#include <cstdint>

// Problem constants
#define Bn   32
#define Cn   256
#define Hn   56
#define Wn   56
#define HWn  (Hn*Wn)           // 3136
#define NTOT (Bn*Cn*HWn)       // 25690112
#define WELEMS (Cn*Cn*9)       // 589824
#define EPSv 1e-5f

// padded packed-activation layout: [b][58 rows][58 cols][8 words]
#define PR   58
#define PPB  (PR*PR)           // 3364 pixels per batch

// ws layout (bytes)
#define F_WABS  0              // float
#define F_SUM   64             // float[256]
#define F_SQ    320            // float[256]
#define STATS_BYTES 4096
#define CLS_OFF_BYTES 4096     // int clst[256][9] = 9216 B
#define WB_OFF_BYTES  16384    // uint32 wb[256][9][8] = 73728 B
#define XB_OFF_BYTES  98304    // uint32 xb[32][58][58][8] = 3444736 B
#define XB_BYTES (Bn*PPB*8*4)

// ---------------------------------------------------------------------------
// Pack weights: wb[co][t=kh*3+kw][wd] bits over ci (bit=1 <=> w<0),
// and reduce sum(|clip(w,-1,1)|) into ws[F_WABS].
__global__ void pack_w_kernel(const float* __restrict__ w,
                              float* __restrict__ wsf,
                              uint32_t* __restrict__ wb) {
    int u = blockIdx.x * 256 + threadIdx.x;   // 72*256 = 18432 words exactly
    float sabs = 0.0f;
    {
        int co = u / 72;
        int r  = u % 72;
        int t  = r >> 3;         // kh*3+kw
        int wd = r & 7;
        uint32_t bits = 0;
        // w layout OIHW: idx = (co*256 + ci)*9 + t
        const float* wp = w + (size_t)co * 2304 + (size_t)(wd * 32) * 9 + t;
        #pragma unroll
        for (int j = 0; j < 32; j++) {
            float wv = wp[(size_t)j * 9];
            sabs += fminf(fabsf(wv), 1.0f);
            bits |= (__float_as_uint(wv) >> 31) << j;
        }
        wb[u] = bits;
    }
    #pragma unroll
    for (int off = 32; off; off >>= 1) sabs += __shfl_down(sabs, off);
    __shared__ float sh[4];
    if ((threadIdx.x & 63) == 0) sh[threadIdx.x >> 6] = sabs;
    __syncthreads();
    if (threadIdx.x == 0)
        atomicAdd(&wsf[F_WABS], sh[0] + sh[1] + sh[2] + sh[3]);
}

// ---------------------------------------------------------------------------
// Boundary-class correction table: clst[co][cls] = sum over missing taps t of
// (256 - 2*wpop[co][t]).  cls = yp*3+xp, yp: 0 none / 1 top / 2 bottom,
// xp: 0 none / 1 left / 2 right.
__global__ void wtable_kernel(const uint32_t* __restrict__ wb,
                              int* __restrict__ clst) {
    int co = threadIdx.x;   // one thread per co, 256 threads, 1 block
    int wp[9];
    #pragma unroll
    for (int t = 0; t < 9; t++) {
        int s = 0;
        #pragma unroll
        for (int wd = 0; wd < 8; wd++) s += __popc(wb[(co * 9 + t) * 8 + wd]);
        wp[t] = 256 - 2 * s;
    }
    int T = wp[0] + wp[1] + wp[2];
    int Bm = wp[6] + wp[7] + wp[8];
    int L = wp[0] + wp[3] + wp[6];
    int R = wp[2] + wp[5] + wp[8];
    int* o = clst + co * 9;
    o[0] = 0;
    o[1] = L;
    o[2] = R;
    o[3] = T;
    o[4] = T + L - wp[0];
    o[5] = T + R - wp[2];
    o[6] = Bm;
    o[7] = Bm + L - wp[6];
    o[8] = Bm + R - wp[8];
}

// ---------------------------------------------------------------------------
// Pack activations into zero-padded layout. bit=1 <=> x<0.
__global__ void pack_x_kernel(const float* __restrict__ x,
                              uint32_t* __restrict__ xb) {
    int v = blockIdx.x * 256 + threadIdx.x;   // 392*256 = 100352 exactly
    int b = v / HWn;
    int p = v - b * HWn;
    int y = p / Wn;
    int xq = p - y * Wn;
    const float* xp = x + (size_t)b * Cn * HWn + p;
    uint32_t r[8];
    #pragma unroll
    for (int wd = 0; wd < 8; wd++) {
        uint32_t bits = 0;
        #pragma unroll
        for (int j = 0; j < 32; j++) {
            bits |= (__float_as_uint(xp[(size_t)(wd * 32 + j) * HWn]) >> 31) << j;
        }
        r[wd] = bits;
    }
    size_t dst = (size_t)b * PPB + (size_t)(y + 1) * PR + (xq + 1);
    uint4* d = (uint4*)xb + dst * 2;
    d[0] = make_uint4(r[0], r[1], r[2], r[3]);
    d[1] = make_uint4(r[4], r[5], r[6], r[7]);
}

// ---------------------------------------------------------------------------
// Binary conv + identity shortcut. Linear pixel mapping, 8 co per thread,
// zero-padded input -> no bounds logic; boundary fixed by clst correction.
__global__ __launch_bounds__(256) void conv_kernel(
    const uint32_t* __restrict__ xb, const uint32_t* __restrict__ wb,
    const int* __restrict__ clst,
    const float* __restrict__ x, const float* __restrict__ wsf,
    float* __restrict__ out) {
    int v = blockIdx.x * 256 + threadIdx.x;   // 0..100351
    int b = v / HWn;
    int p = v - b * HWn;
    int y = p / Wn;
    int xq = p - y * Wn;
    int co0 = blockIdx.y * 8;

    const float mean_val = wsf[F_WABS] * (1.0f / (float)WELEMS);

    // window start: padded (row y+dh, col xq), 3 pixels = 6 uint4 per row
    const uint4* base = (const uint4*)xb + ((size_t)b * PPB + (size_t)y * PR + xq) * 2;

    int acc[8] = {0, 0, 0, 0, 0, 0, 0, 0};
    #pragma unroll
    for (int dh = 0; dh < 3; dh++) {
        uint32_t nw[24];
        const uint4* rp = base + dh * (PR * 2);
        #pragma unroll
        for (int q = 0; q < 6; q++) {
            uint4 t = rp[q];
            nw[q * 4 + 0] = t.x; nw[q * 4 + 1] = t.y;
            nw[q * 4 + 2] = t.z; nw[q * 4 + 3] = t.w;
        }
        #pragma unroll
        for (int dw = 0; dw < 3; dw++) {
            #pragma unroll
            for (int cs = 0; cs < 8; cs++) {
                const uint32_t* wp = wb + ((size_t)(co0 + cs) * 9 + (dh * 3 + dw)) * 8;
                int pc = acc[cs];
                #pragma unroll
                for (int wd = 0; wd < 8; wd++)
                    pc += __popc(nw[dw * 8 + wd] ^ wp[wd]);
                acc[cs] = pc;
            }
        }
    }

    int yp = (y == 0) ? 1 : ((y == 55) ? 2 : 0);
    int xp = (xq == 0) ? 1 : ((xq == 55) ? 2 : 0);
    int cls = yp * 3 + xp;

    #pragma unroll
    for (int cs = 0; cs < 8; cs++) {
        int corr = clst[(co0 + cs) * 9 + cls];
        size_t idx = ((size_t)b * Cn + (co0 + cs)) * HWn + p;
        float dot = (float)(2304 - 2 * acc[cs] - corr);
        out[idx] = fmaf(mean_val, dot, x[idx]);
    }
}

// ---------------------------------------------------------------------------
// Per-channel stats: one block per (b,c) plane; atomics into ws.
__global__ void stats_kernel(const float* __restrict__ out,
                             float* __restrict__ wsf) {
    int plane = blockIdx.x;   // b*256 + c
    const float4* p = (const float4*)(out + (size_t)plane * HWn);
    float s = 0.0f, q = 0.0f;
    for (int i = threadIdx.x; i < HWn / 4; i += 256) {
        float4 v = p[i];
        s += v.x + v.y + v.z + v.w;
        q += v.x * v.x + v.y * v.y + v.z * v.z + v.w * v.w;
    }
    #pragma unroll
    for (int off = 32; off; off >>= 1) {
        s += __shfl_down(s, off);
        q += __shfl_down(q, off);
    }
    __shared__ float ss[4], sq[4];
    if ((threadIdx.x & 63) == 0) { ss[threadIdx.x >> 6] = s; sq[threadIdx.x >> 6] = q; }
    __syncthreads();
    if (threadIdx.x == 0) {
        int c = plane & 255;
        atomicAdd(&wsf[F_SUM + c], ss[0] + ss[1] + ss[2] + ss[3]);
        atomicAdd(&wsf[F_SQ  + c], sq[0] + sq[1] + sq[2] + sq[3]);
    }
}

// ---------------------------------------------------------------------------
// BN finalize (per-plane, computed from ws sums) + normalize + ReLU, in place.
__global__ void epilogue_kernel(float* __restrict__ out,
                                const float* __restrict__ wsf,
                                const float* __restrict__ g,
                                const float* __restrict__ bt) {
    int plane = blockIdx.x;   // b*256 + c
    int c = plane & 255;
    const float n = (float)(Bn * HWn);
    float mean = wsf[F_SUM + c] / n;
    float var  = wsf[F_SQ + c] / n - mean * mean;
    float sc = g[c] * rsqrtf(var + EPSv);
    float sh = bt[c] - mean * sc;
    float4* o4 = (float4*)(out + (size_t)plane * HWn);
    for (int i = threadIdx.x; i < HWn / 4; i += 256) {
        float4 v = o4[i];
        v.x = fmaxf(fmaf(v.x, sc, sh), 0.0f);
        v.y = fmaxf(fmaf(v.y, sc, sh), 0.0f);
        v.z = fmaxf(fmaf(v.z, sc, sh), 0.0f);
        v.w = fmaxf(fmaf(v.w, sc, sh), 0.0f);
        o4[i] = v;
    }
}

// ---------------------------------------------------------------------------
extern "C" void kernel_launch(void* const* d_in, const int* in_sizes, int n_in,
                              void* d_out, int out_size, void* d_ws, size_t ws_size,
                              hipStream_t stream) {
    const float* x     = (const float*)d_in[0];
    const float* w     = (const float*)d_in[1];
    const float* gamma = (const float*)d_in[2];
    const float* beta  = (const float*)d_in[3];
    float* out = (float*)d_out;

    float*    wsf  = (float*)d_ws;
    int*      clst = (int*)((char*)d_ws + CLS_OFF_BYTES);
    uint32_t* wb   = (uint32_t*)((char*)d_ws + WB_OFF_BYTES);
    uint32_t* xb   = (uint32_t*)((char*)d_ws + XB_OFF_BYTES);

    hipMemsetAsync(d_ws, 0, STATS_BYTES, stream);
    hipMemsetAsync(xb, 0, XB_BYTES, stream);
    pack_w_kernel<<<dim3(72), dim3(256), 0, stream>>>(w, wsf, wb);
    wtable_kernel<<<dim3(1), dim3(256), 0, stream>>>(wb, clst);
    pack_x_kernel<<<dim3(392), dim3(256), 0, stream>>>(x, xb);
    conv_kernel<<<dim3(392, 32), dim3(256), 0, stream>>>(xb, wb, clst, x, wsf, out);
    stats_kernel<<<dim3(Bn * Cn), dim3(256), 0, stream>>>(out, wsf);
    epilogue_kernel<<<dim3(Bn * Cn), dim3(256), 0, stream>>>(out, wsf, gamma, beta);
}